// Round 2
// baseline (2297.080 us; speedup 1.0000x reference)
//
#include <hip/hip_runtime.h>
#include <stdint.h>

#define T_STEPS 1024
#define BATCH   512
#define IN_DIM  64
#define HID_DIM 256
#define OUT_DIM 32

// ===========================================================================
// NUMERICS CONTRACT (validated by R4 pass, absmax 7.8e-3 vs 5.75e-2):
//   * dot products: single fp32 accumulator, k ASCENDING, fmaf each step
//   * bias: separately-rounded fp32 add AFTER the chain
//   * LIF: mem = ((0.92f*mem) + cur) - reset, three separate fp32 ops,
//          reset from PREVIOUS mem, compares mem > 1.0f
// Any reassociation flips spikes (binary outputs, 16.7M decisions). Do not.
// Two h-chains per thread do NOT reassociate: each acc is its own
// single-accumulator ascending chain.
// ===========================================================================

#define GLOAD_LDS16(GP, LP)                                                \
    __builtin_amdgcn_global_load_lds(                                      \
        (const __attribute__((address_space(1))) void*)(GP),               \
        (__attribute__((address_space(3))) void*)(LP), 16, 0, 0)

// ---------------------------------------------------------------------------
// Phase 1: fused GEMM1 + LIF1.
// v3: LDS-writeback-bound fix. Each thread now owns TWO h chains
// (hA = tid&127, hB = hA+128), so each broadcast x quad read from LDS feeds
// 8 fmas instead of 4 -> LDS traffic per fma halves (model: 437 -> 218 us
// ceiling; VALU floor ~126 us). Block covers 2 batches (bl = tid>>7), grid
// 256 blocks = 1 block/CU, 1 wave/SIMD; ILP comes from the two independent
// chains. W1 rows (128 regs) pinned in VGPRs via empty asm. x staged through
// LDS in 32-step chunks, double-buffered, global_load_lds width=16.
// Unroll capped at 4 steps to bound I$ footprint.
// ---------------------------------------------------------------------------
#define CHUNK 32

__global__ __launch_bounds__(256, 1) void snn_l1(
    const float* __restrict__ x,                  // [T,B,64]
    const float* __restrict__ W1,                 // [256,64]
    const float* __restrict__ b1,                 // [256]
    unsigned long long* __restrict__ bits)        // [T,B,4] u64 ballots
{
    const int b0   = blockIdx.x * 2;
    const int tid  = threadIdx.x;
    const int lane = tid & 63;
    const int wv   = tid >> 6;        // 0..3
    const int bl   = tid >> 7;        // 0/1: which batch row this wave uses
    const int hA   = tid & 127;
    const int hB   = hA + 128;
    const int b    = b0 + bl;

    __shared__ __align__(16) float xs[2][CHUNK][2][IN_DIM];   // 2 x 16 KB

    float wA[IN_DIM], wB[IN_DIM];
#pragma unroll
    for (int k = 0; k < IN_DIM; ++k) wA[k] = W1[hA * IN_DIM + k];
#pragma unroll
    for (int k = 0; k < IN_DIM; ++k) wB[k] = W1[hB * IN_DIM + k];
    // Pin both rows in VGPRs (loads must not be sunk into the t-loop).
#pragma unroll
    for (int k = 0; k < IN_DIM; ++k) asm volatile("" : "+v"(wA[k]));
#pragma unroll
    for (int k = 0; k < IN_DIM; ++k) asm volatile("" : "+v"(wB[k]));
    const float biasA = b1[hA];
    const float biasB = b1[hB];

    // Staging: one buffer = CHUNK*2*64 floats = 1024 float4 slots; 256
    // threads x 4 passes x 16B. LDS dest linear in slot (wave-uniform base +
    // lane*16 within each pass); global source per-lane.
#define STAGE(BUF, CT)                                                     \
    {                                                                      \
        _Pragma("unroll")                                                  \
        for (int r = 0; r < 4; ++r) {                                      \
            const int slot = r * 256 + tid;                                \
            const int step = slot >> 5;                                    \
            const int rem  = slot & 31;                                    \
            const int bb   = rem >> 4;                                     \
            const int f4   = rem & 15;                                     \
            const float4* gp = (const float4*)x +                          \
                ((size_t)((CT) * CHUNK + step) * BATCH + b0 + bb) * 16 + f4; \
            GLOAD_LDS16(gp, (float*)xs + (size_t)(BUF) * (CHUNK * 2 * IN_DIM) \
                                + slot * 4);                               \
        }                                                                  \
    }

    float memA = 0.0f, memB = 0.0f;

    STAGE(0, 0)

    for (int c = 0; c < T_STEPS / CHUNK; ++c) {
        const int cb = c & 1;
        // __syncthreads drains vmcnt (global_load_lds) then barriers:
        // buf[cb] fully staged; everyone done reading buf[cb^1].
        __syncthreads();
        if (c + 1 < T_STEPS / CHUNK) STAGE(cb ^ 1, c + 1)

#pragma unroll 4
        for (int s = 0; s < CHUNK; ++s) {
            const float4* xp = (const float4*)(&xs[cb][s][bl][0]);
            float aA = 0.0f, aB = 0.0f;
#pragma unroll
            for (int i = 0; i < 16; ++i) {
                const float4 u = xp[i];         // broadcast ds_read_b128
                aA = fmaf(u.x, wA[4 * i + 0], aA);
                aB = fmaf(u.x, wB[4 * i + 0], aB);
                aA = fmaf(u.y, wA[4 * i + 1], aA);
                aB = fmaf(u.y, wB[4 * i + 1], aB);
                aA = fmaf(u.z, wA[4 * i + 2], aA);
                aB = fmaf(u.z, wB[4 * i + 2], aB);
                aA = fmaf(u.w, wA[4 * i + 3], aA);
                aB = fmaf(u.w, wB[4 * i + 3], aB);
            }
            const int t = c * CHUNK + s;
            {
                const float cur1 = __fadd_rn(aA, biasA);
                const float r1 = (memA > 1.0f) ? 1.0f : 0.0f;
                memA = __fsub_rn(__fadd_rn(__fmul_rn(0.92f, memA), cur1), r1);
                const unsigned long long bm = __ballot(memA > 1.0f);
                if (lane == 0)
                    bits[((size_t)t * BATCH + b) * 4 + (wv & 1)] = bm;
            }
            {
                const float cur1 = __fadd_rn(aB, biasB);
                const float r1 = (memB > 1.0f) ? 1.0f : 0.0f;
                memB = __fsub_rn(__fadd_rn(__fmul_rn(0.92f, memB), cur1), r1);
                const unsigned long long bm = __ballot(memB > 1.0f);
                if (lane == 0)
                    bits[((size_t)t * BATCH + b) * 4 + 2 + (wv & 1)] = bm;
            }
        }
    }
#undef STAGE
}

// ---------------------------------------------------------------------------
// Phase 2: GEMM2. v3: all 8 output groups merged into ONE kernel (og loop
// inside). Why: previously each 128B cur2 line was written 16B-at-a-time by
// 8 DIFFERENT blocks (likely on different XCDs -> non-coherent L2s ->
// partial-line writebacks, up to 8x WRITE traffic), and bits were fetched 8x.
// Now one wave completes its lines locally, bits read once, bit-extract
// VALU cost /8. Exact k-ascending chain per output preserved.
// ---------------------------------------------------------------------------
__global__ __launch_bounds__(256, 4) void snn_l2gemm(
    const uint32_t* __restrict__ bits,   // [T*B, 8] u32
    const float* __restrict__ W2,        // [32,256]
    const float* __restrict__ b2,        // [32]
    float* __restrict__ cur2)            // [T*B, 32]
{
    const size_t tb = (size_t)blockIdx.x * 256 + threadIdx.x;  // 0..T*B-1

    const uint4 wAq = ((const uint4*)bits)[tb * 2 + 0];
    const uint4 wBq = ((const uint4*)bits)[tb * 2 + 1];
    const uint32_t wds[8] = {wAq.x, wAq.y, wAq.z, wAq.w,
                             wBq.x, wBq.y, wBq.z, wBq.w};

#pragma unroll 1
    for (int og = 0; og < 8; ++og) {
        const float* __restrict__ wr0 = W2 + (og * 4 + 0) * HID_DIM;
        const float* __restrict__ wr1 = W2 + (og * 4 + 1) * HID_DIM;
        const float* __restrict__ wr2 = W2 + (og * 4 + 2) * HID_DIM;
        const float* __restrict__ wr3 = W2 + (og * 4 + 3) * HID_DIM;

        float a0 = 0.0f, a1 = 0.0f, a2 = 0.0f, a3 = 0.0f;

#pragma unroll
        for (int c = 0; c < 16; ++c) {            // 16 chunks x 16 k
            float r0[16], r1[16], r2[16], r3[16];
#pragma unroll
            for (int i = 0; i < 16; ++i) {
                const int k = c * 16 + i;
                r0[i] = wr0[k];                   // wave-uniform -> s_load
                r1[i] = wr1[k];
                r2[i] = wr2[k];
                r3[i] = wr3[k];
            }
            const uint32_t word = wds[c >> 1];
            const int      base = (c & 1) * 16;
#pragma unroll
            for (int i = 0; i < 16; ++i) {
                const float sf = (float)((word >> (base + i)) & 1u);
                a0 = fmaf(sf, r0[i], a0);         // exact: fl(acc + w) or acc
                a1 = fmaf(sf, r1[i], a1);
                a2 = fmaf(sf, r2[i], a2);
                a3 = fmaf(sf, r3[i], a3);
            }
        }

        a0 = __fadd_rn(a0, b2[og * 4 + 0]);       // separately-rounded bias
        a1 = __fadd_rn(a1, b2[og * 4 + 1]);
        a2 = __fadd_rn(a2, b2[og * 4 + 2]);
        a3 = __fadd_rn(a3, b2[og * 4 + 3]);

        ((float4*)cur2)[tb * (OUT_DIM / 4) + og] = make_float4(a0, a1, a2, a3);
    }
}

// ---------------------------------------------------------------------------
// Phase 3: LIF2 t-scan. Thread = (b,o), 16384 chains. v3: 16-deep load
// batching (was 8) to keep more HBM/L3 requests in flight on this
// latency-bound serial chain.
// ---------------------------------------------------------------------------
__global__ __launch_bounds__(256, 4) void snn_l2scan(
    float* __restrict__ spk_io,          // [T,B,32]: cur2 in, spk2 out
    float* __restrict__ mem_out)         // [T,B,32]
{
    const int tid = threadIdx.x;
    const int o   = tid & (OUT_DIM - 1);
    const int b   = blockIdx.x * 8 + (tid >> 5);

    float* p = spk_io  + (size_t)b * OUT_DIM + o;
    float* m = mem_out + (size_t)b * OUT_DIM + o;
    const size_t step = (size_t)BATCH * OUT_DIM;

    float mem2 = 0.0f;
    for (int t = 0; t < T_STEPS; t += 16) {
        float c[16];
#pragma unroll
        for (int u = 0; u < 16; ++u) c[u] = p[(size_t)(t + u) * step];
#pragma unroll
        for (int u = 0; u < 16; ++u) {
            const float r2 = (mem2 > 1.0f) ? 1.0f : 0.0f;
            mem2 = __fsub_rn(__fadd_rn(__fmul_rn(0.92f, mem2), c[u]), r2);
            p[(size_t)(t + u) * step] = (mem2 > 1.0f) ? 1.0f : 0.0f;
            m[(size_t)(t + u) * step] = mem2;
        }
    }
}

extern "C" void kernel_launch(void* const* d_in, const int* in_sizes, int n_in,
                              void* d_out, int out_size, void* d_ws, size_t ws_size,
                              hipStream_t stream) {
    const float* x  = (const float*)d_in[0];  // [T,B,64] fp32
    const float* W1 = (const float*)d_in[1];  // [256,64] fp32
    const float* b1 = (const float*)d_in[2];  // [256]    fp32
    const float* W2 = (const float*)d_in[3];  // [32,256] fp32
    const float* b2 = (const float*)d_in[4];  // [32]     fp32

    float* out_spk = (float*)d_out;                                  // 67 MB
    float* out_mem = out_spk + (size_t)T_STEPS * BATCH * OUT_DIM;    // 67 MB

    // Scratch plan (zero d_ws usage):
    //   bits (16 MB) live at the start of out_mem; consumed entirely by
    //   phase 2 before phase 3 overwrites that region with mem2.
    //   cur2 lives in out_spk; phase 3 overwrites it in-place with spk2.
    unsigned long long* bits = (unsigned long long*)out_mem;

    snn_l1<<<BATCH / 2, 256, 0, stream>>>(x, W1, b1, bits);

    snn_l2gemm<<<T_STEPS * BATCH / 256, 256, 0, stream>>>(
        (const uint32_t*)bits, W2, b2, out_spk);

    snn_l2scan<<<BATCH / 8, 256, 0, stream>>>(out_spk, out_mem);
}

// Round 3
// 999.818 us; speedup vs baseline: 2.2975x; 2.2975x over previous
//
#include <hip/hip_runtime.h>
#include <stdint.h>

#define T_STEPS 1024
#define BATCH   512
#define IN_DIM  64
#define HID_DIM 256
#define OUT_DIM 32

// ===========================================================================
// NUMERICS CONTRACT (validated by R4 pass, absmax 7.8e-3 vs 5.75e-2):
//   * dot products: single fp32 accumulator, k ASCENDING, fmaf each step
//   * bias: separately-rounded fp32 add AFTER the chain
//   * LIF: mem = ((0.92f*mem) + cur) - reset, three separate fp32 ops,
//          reset from PREVIOUS mem, compares mem > 1.0f
// Any reassociation flips spikes (binary outputs, 16.7M decisions). Do not.
// ===========================================================================
// LESSON (R2 post-mortem): cur2 lines are 128 B = one thread's 32 outputs.
// Partial-line stores separated in time cause L2 RMW amplification (measured
// 4.9 GB HBM traffic vs 85 MB ideal). All 8 float4 stores of a line must be
// issued back-to-back so the line is fully covered while resident.
// ===========================================================================

#define GLOAD_LDS16(GP, LP)                                                \
    __builtin_amdgcn_global_load_lds(                                      \
        (const __attribute__((address_space(1))) void*)(GP),               \
        (__attribute__((address_space(3))) void*)(LP), 16, 0, 0)

// ---------------------------------------------------------------------------
// Phase 1: fused GEMM1 + LIF1. R1-verified version (390 us, VALUBusy 70%).
// Thread = (b,h); t sequential. W1 row pinned in VGPRs via empty asm
// (compiler otherwise sinks the loads into the t-loop: VGPR=40 bug).
// x staged through LDS in 32-step chunks, double-buffered, via
// global_load_lds width=16 -> prefetch depth 32 steps. Two t-steps' FMA
// chains interleaved (acc0/acc1) for dep-latency ILP.
// ---------------------------------------------------------------------------
#define CHUNK 32

__global__ __launch_bounds__(256, 2) void snn_l1(
    const float* __restrict__ x,                  // [T,B,64]
    const float* __restrict__ W1,                 // [256,64]
    const float* __restrict__ b1,                 // [256]
    unsigned long long* __restrict__ bits)        // [T,B,4] u64 ballots
{
    const int b    = blockIdx.x;
    const int h    = threadIdx.x;
    const int wv   = h >> 6;
    const int lane = h & 63;

    __shared__ __align__(16) float xs[2][CHUNK][IN_DIM];   // 2 x 8 KB

    float w1r[IN_DIM];
#pragma unroll
    for (int k = 0; k < IN_DIM; ++k) w1r[k] = W1[h * IN_DIM + k];
    // Pin the row in VGPRs: each asm consumes the loaded value, so the loads
    // cannot be sunk into the t-loop.
#pragma unroll
    for (int k = 0; k < IN_DIM; ++k) asm volatile("" : "+v"(w1r[k]));
    const float bias1 = b1[h];

    // Staging: one buffer = CHUNK*64 floats = 512 float4 slots. Thread covers
    // slots (r*4+wv)*64+lane, r=0..1. LDS dest linear (wave-uniform base +
    // lane*16) as global_load_lds requires; global source per-lane.
#define STAGE(BUF, CT)                                                     \
    {                                                                      \
        _Pragma("unroll")                                                  \
        for (int r = 0; r < 2; ++r) {                                      \
            const int slot = (r * 4 + wv) * 64 + lane;                     \
            const int step = slot >> 4;                                    \
            const int f4   = slot & 15;                                    \
            const float4* gp = (const float4*)x +                          \
                ((size_t)((CT) * CHUNK + step) * BATCH + b) * 16 + f4;     \
            GLOAD_LDS16(gp, &xs[BUF][0][0] + slot * 4);                    \
        }                                                                  \
    }

    float mem1 = 0.0f;

    STAGE(0, 0)

    for (int c = 0; c < T_STEPS / CHUNK; ++c) {
        const int cb = c & 1;
        // __syncthreads drains each wave's own global_load_lds (vmcnt) then
        // barriers: buf[cb] fully staged; everyone done reading buf[cb^1].
        __syncthreads();
        if (c + 1 < T_STEPS / CHUNK) STAGE(cb ^ 1, c + 1)

#pragma unroll
        for (int s = 0; s < CHUNK; s += 2) {
            const float4* xp0 = (const float4*)(&xs[cb][s][0]);
            const float4* xp1 = (const float4*)(&xs[cb][s + 1][0]);
            float acc0 = 0.0f, acc1 = 0.0f;
#pragma unroll
            for (int i = 0; i < 16; ++i) {
                const float4 u = xp0[i];        // broadcast ds_read_b128
                const float4 v = xp1[i];
                acc0 = fmaf(u.x, w1r[4 * i + 0], acc0);
                acc0 = fmaf(u.y, w1r[4 * i + 1], acc0);
                acc0 = fmaf(u.z, w1r[4 * i + 2], acc0);
                acc0 = fmaf(u.w, w1r[4 * i + 3], acc0);
                acc1 = fmaf(v.x, w1r[4 * i + 0], acc1);
                acc1 = fmaf(v.y, w1r[4 * i + 1], acc1);
                acc1 = fmaf(v.z, w1r[4 * i + 2], acc1);
                acc1 = fmaf(v.w, w1r[4 * i + 3], acc1);
            }
            const int t0 = c * CHUNK + s;
            {
                const float cur1 = __fadd_rn(acc0, bias1);
                const float r1 = (mem1 > 1.0f) ? 1.0f : 0.0f;
                mem1 = __fsub_rn(__fadd_rn(__fmul_rn(0.92f, mem1), cur1), r1);
                const unsigned long long bm = __ballot(mem1 > 1.0f);
                if (lane == 0)
                    bits[((size_t)t0 * BATCH + b) * 4 + wv] = bm;
            }
            {
                const float cur1 = __fadd_rn(acc1, bias1);
                const float r1 = (mem1 > 1.0f) ? 1.0f : 0.0f;
                mem1 = __fsub_rn(__fadd_rn(__fmul_rn(0.92f, mem1), cur1), r1);
                const unsigned long long bm = __ballot(mem1 > 1.0f);
                if (lane == 0)
                    bits[((size_t)(t0 + 1) * BATCH + b) * 4 + wv] = bm;
            }
        }
    }
#undef STAGE
}

// ---------------------------------------------------------------------------
// Phase 2: GEMM2. v4: single kernel, og FULLY UNROLLED with persistent
// acc[8][4] (all indices static after unroll -> registers, no scratch), and
// all 8 float4 stores of the thread's 128-B cur2 line issued back-to-back
// in the epilogue -> full-line write, no RMW amplification (the R2 bug).
// bits read once per thread; W2 rows wave-uniform -> s_loads.
// Exact k-ascending chain per output preserved.
// ---------------------------------------------------------------------------
__global__ __launch_bounds__(256, 4) void snn_l2gemm(
    const uint32_t* __restrict__ bits,   // [T*B, 8] u32
    const float* __restrict__ W2,        // [32,256]
    const float* __restrict__ b2,        // [32]
    float* __restrict__ cur2)            // [T*B, 32]
{
    const size_t tb = (size_t)blockIdx.x * 256 + threadIdx.x;  // 0..T*B-1

    const uint4 wAq = ((const uint4*)bits)[tb * 2 + 0];
    const uint4 wBq = ((const uint4*)bits)[tb * 2 + 1];
    const uint32_t wds[8] = {wAq.x, wAq.y, wAq.z, wAq.w,
                             wBq.x, wBq.y, wBq.z, wBq.w};

    float acc[8][4];

#pragma unroll
    for (int og = 0; og < 8; ++og) {
        const float* __restrict__ wr0 = W2 + (og * 4 + 0) * HID_DIM;
        const float* __restrict__ wr1 = W2 + (og * 4 + 1) * HID_DIM;
        const float* __restrict__ wr2 = W2 + (og * 4 + 2) * HID_DIM;
        const float* __restrict__ wr3 = W2 + (og * 4 + 3) * HID_DIM;

        float a0 = 0.0f, a1 = 0.0f, a2 = 0.0f, a3 = 0.0f;

#pragma unroll
        for (int c = 0; c < 16; ++c) {            // 16 chunks x 16 k
            float r0[16], r1[16], r2[16], r3[16];
#pragma unroll
            for (int i = 0; i < 16; ++i) {
                const int k = c * 16 + i;
                r0[i] = wr0[k];                   // wave-uniform -> s_load
                r1[i] = wr1[k];
                r2[i] = wr2[k];
                r3[i] = wr3[k];
            }
            const uint32_t word = wds[c >> 1];    // static after unroll
            const int      base = (c & 1) * 16;
#pragma unroll
            for (int i = 0; i < 16; ++i) {
                const float sf = (float)((word >> (base + i)) & 1u);
                a0 = fmaf(sf, r0[i], a0);         // exact: fl(acc + w) or acc
                a1 = fmaf(sf, r1[i], a1);
                a2 = fmaf(sf, r2[i], a2);
                a3 = fmaf(sf, r3[i], a3);
            }
        }

        acc[og][0] = a0;  acc[og][1] = a1;
        acc[og][2] = a2;  acc[og][3] = a3;
    }

    // Epilogue: bias (separately rounded), then the whole 128-B line in 8
    // back-to-back float4 stores -> fully-covered line, no RFO round-trips.
#pragma unroll
    for (int og = 0; og < 8; ++og) {
        const float4 r = make_float4(
            __fadd_rn(acc[og][0], b2[og * 4 + 0]),
            __fadd_rn(acc[og][1], b2[og * 4 + 1]),
            __fadd_rn(acc[og][2], b2[og * 4 + 2]),
            __fadd_rn(acc[og][3], b2[og * 4 + 3]));
        ((float4*)cur2)[tb * (OUT_DIM / 4) + og] = r;
    }
}

// ---------------------------------------------------------------------------
// Phase 3: LIF2 t-scan. R1-verified version. Thread = (b,o), 16384 chains.
// Reads cur2 in-place from the out_spk region and overwrites it with spk2;
// mem2 to out_mem. 8-deep load batching.
// ---------------------------------------------------------------------------
__global__ __launch_bounds__(256, 4) void snn_l2scan(
    float* __restrict__ spk_io,          // [T,B,32]: cur2 in, spk2 out
    float* __restrict__ mem_out)         // [T,B,32]
{
    const int tid = threadIdx.x;
    const int o   = tid & (OUT_DIM - 1);
    const int b   = blockIdx.x * 8 + (tid >> 5);

    float* p = spk_io  + (size_t)b * OUT_DIM + o;
    float* m = mem_out + (size_t)b * OUT_DIM + o;
    const size_t step = (size_t)BATCH * OUT_DIM;

    float mem2 = 0.0f;
    for (int t = 0; t < T_STEPS; t += 8) {
        float c[8];
#pragma unroll
        for (int u = 0; u < 8; ++u) c[u] = p[(size_t)(t + u) * step];
#pragma unroll
        for (int u = 0; u < 8; ++u) {
            const float r2 = (mem2 > 1.0f) ? 1.0f : 0.0f;
            mem2 = __fsub_rn(__fadd_rn(__fmul_rn(0.92f, mem2), c[u]), r2);
            p[(size_t)(t + u) * step] = (mem2 > 1.0f) ? 1.0f : 0.0f;
            m[(size_t)(t + u) * step] = mem2;
        }
    }
}

extern "C" void kernel_launch(void* const* d_in, const int* in_sizes, int n_in,
                              void* d_out, int out_size, void* d_ws, size_t ws_size,
                              hipStream_t stream) {
    const float* x  = (const float*)d_in[0];  // [T,B,64] fp32
    const float* W1 = (const float*)d_in[1];  // [256,64] fp32
    const float* b1 = (const float*)d_in[2];  // [256]    fp32
    const float* W2 = (const float*)d_in[3];  // [32,256] fp32
    const float* b2 = (const float*)d_in[4];  // [32]     fp32

    float* out_spk = (float*)d_out;                                  // 67 MB
    float* out_mem = out_spk + (size_t)T_STEPS * BATCH * OUT_DIM;    // 67 MB

    // Scratch plan (zero d_ws usage):
    //   bits (16 MB) live at the start of out_mem; consumed entirely by
    //   phase 2 before phase 3 overwrites that region with mem2.
    //   cur2 lives in out_spk; phase 3 overwrites it in-place with spk2.
    unsigned long long* bits = (unsigned long long*)out_mem;

    snn_l1<<<BATCH, 256, 0, stream>>>(x, W1, b1, bits);

    snn_l2gemm<<<T_STEPS * BATCH / 256, 256, 0, stream>>>(
        (const uint32_t*)bits, W2, b2, out_spk);

    snn_l2scan<<<BATCH / 8, 256, 0, stream>>>(out_spk, out_mem);
}